// Round 15
// baseline (62.526 us; speedup 1.0000x reference)
//
#include <hip/hip_runtime.h>
#include <math.h>

#define NBOX   4096
#define NTHR   1024
#define MAXDET 300
#define CAP    3968          // fallback path
#define NWORDS (NBOX / 32)

typedef unsigned long long ull;

__device__ __forceinline__ float clipf(float v, float hi) {
  return fminf(fmaxf(v, 0.0f), hi);
}

__device__ __forceinline__ float getimg(const int* img_i) {
  int iv = *img_i;
  return (iv > 0 && iv < (1 << 24)) ? (float)iv : __int_as_float(iv);
}

// comparator macros: "up" (e&K)==0 => descending run (matches argsort(-key))
#define CSWAP_REG(va, vb, eo, K) { int e_ = wbase + (eo) + lane;                     \
    if ((((e_) & (K)) == 0) ? ((va) < (vb)) : ((va) > (vb))) { ull t_=(va); (va)=(vb); (vb)=t_; } }
#define CSWAP_SHFL(vr, eo, K) { int e_ = wbase + (eo) + lane;                        \
    ull c_ = __shfl_xor((vr), j);                                                    \
    bool km_ = ((((e_) & (K)) == 0) == ((lane & j) == 0));                           \
    (vr) = km_ ? ((vr) > c_ ? (vr) : c_) : ((vr) < c_ ? (vr) : c_); }
#define LOCALPHASES(jmax, K) { for (int j = (jmax); j >= 1; j >>= 1) {               \
    if (j == 128)      { CSWAP_REG(v0, v2, 0, K);  CSWAP_REG(v1, v3, 64, K);  }      \
    else if (j == 64)  { CSWAP_REG(v0, v1, 0, K);  CSWAP_REG(v2, v3, 128, K); }      \
    else { CSWAP_SHFL(v0, 0, K); CSWAP_SHFL(v1, 64, K); CSWAP_SHFL(v2, 128, K); CSWAP_SHFL(v3, 192, K); } } }

__device__ __forceinline__ void emit_one(ull key, int l, int b, int N,
    const float* boxes, const int* labels, float fimg, float offs,
    int* ws_sorted, float4* obox, float* area)
{
  unsigned orig = 0xFFFFFFFFu - (unsigned)(key & 0xFFFFFFFFull);
  ws_sorted[(size_t)b * N + l] = (int)orig;
  const float4* bx4 = (const float4*)(boxes + (size_t)b * N * 4);
  float4 bb = bx4[orig];
  float off = (float)labels[(size_t)b * N + orig] * offs;
  bb.x = clipf(bb.x, fimg) + off;
  bb.y = clipf(bb.y, fimg) + off;
  bb.z = clipf(bb.z, fimg) + off;
  bb.w = clipf(bb.w, fimg) + off;
  obox[(size_t)b * NBOX + l] = bb;
  area[(size_t)b * NBOX + l] = fmaxf(bb.z - bb.x, 0.0f) * fmaxf(bb.w - bb.y, 0.0f);
}

// =================== SM: fused keys + 4x segment sort + top-1024 merge + prep ===================
// 1024 threads: group s = tid>>8 sorts segment s (proven sort_seg network);
// then the proven merge_top network runs in-block from LDS.
__global__ __launch_bounds__(NTHR)
void sort_merge(const float* __restrict__ scores,
                const int*   __restrict__ labels,
                const float* __restrict__ cls_w,
                const float* __restrict__ boxes,
                const int*   __restrict__ img_i,
                ull* __restrict__ ws_keys,
                int* __restrict__ ws_sorted,
                int* __restrict__ ws_V,
                int* __restrict__ ws_done,
                float4* __restrict__ obox,
                float*  __restrict__ area,
                int N)
{
  __shared__ ull ks[4096];        // 32 KB: all four sorted segments
  __shared__ ull ksh[2][1024];    // 16 KB: merge buffers
  __shared__ int cnt[4];

  const int b = blockIdx.x;
  const int tid = threadIdx.x;
  const int lane = tid & 63;
  const int wave = tid >> 6;        // 0..15
  const int wv = wave & 3;
  const int wbase = wv * 256;       // local element base within a 1024 region
  const int s = tid >> 8;           // segment 0..3
  const int gtid = tid & 255;
  const float* sc = scores + (size_t)b * N;
  const int*   lb = labels + (size_t)b * N;

  if (tid < 4) cnt[tid] = 0;

  // ---- build keys for own segment (registers) ----
  ull v0, v1, v2, v3;
  int vc = 0;
  #define BUILD(vm, mo) { int l_ = wbase + (mo) + lane; int gi = s * 1024 + l_;      \
      float sv = sc[gi]; ull key = (ull)(0xFFFFFFFFu - (unsigned)gi);                \
      if (sv > 0.3f) { float w_ = sv * cls_w[lb[gi]]; unsigned ub = __float_as_uint(w_); \
        ub = (ub & 0x80000000u) ? ~ub : (ub | 0x80000000u);                          \
        key |= ((ull)ub << 32); ++vc; }                                              \
      vm = key; }
  BUILD(v0, 0) BUILD(v1, 64) BUILD(v2, 128) BUILD(v3, 192)
  #undef BUILD

  // ---- segment sort: local stages k=2..256 (no barriers) ----
  for (int k2 = 2; k2 <= 256; k2 <<= 1) { LOCALPHASES(k2 >> 1, k2); }

  #define STV { ks[s*1024 + wbase + lane] = v0; ks[s*1024 + wbase + 64 + lane] = v1; \
                ks[s*1024 + wbase + 128 + lane] = v2; ks[s*1024 + wbase + 192 + lane] = v3; }
  #define LDV { v0 = ks[s*1024 + wbase + lane]; v1 = ks[s*1024 + wbase + 64 + lane]; \
                v2 = ks[s*1024 + wbase + 128 + lane]; v3 = ks[s*1024 + wbase + 192 + lane]; }
  #define CROSS(J, K) { for (int i = gtid; i < 1024; i += 256) { int l2 = i ^ (J);   \
      if (l2 > i) { ull a = ks[s*1024 + i], c = ks[s*1024 + l2];                     \
        if ((((i) & (K)) == 0) ? (a < c) : (a > c)) { ks[s*1024 + i] = c; ks[s*1024 + l2] = a; } } } }

  STV; __syncthreads();
  atomicAdd(&cnt[s], vc);
  CROSS(256, 512); __syncthreads();
  LDV; LOCALPHASES(128, 512);
  STV; __syncthreads();
  CROSS(512, 1024); __syncthreads();
  CROSS(256, 1024); __syncthreads();
  LDV; LOCALPHASES(128, 1024);
  STV;                              // sorted segment back to LDS
  // persist segment keys for the rare path
  {
    ull* kb = ws_keys + (size_t)b * NBOX + s * 1024;
    kb[wbase + lane]       = v0;
    kb[wbase + 64 + lane]  = v1;
    kb[wbase + 128 + lane] = v2;
    kb[wbase + 192 + lane] = v3;
  }
  __syncthreads();
  #undef STV
  #undef LDV
  #undef CROSS

  // ---- merge phase (proven merge_top network; tid<512 active) ----
  const bool act = (tid < 512);
  const int g2 = wave >> 2;         // 0..3; only 0,1 active

  #define STVG(arr) { (arr)[wbase + lane] = v0; (arr)[wbase + 64 + lane] = v1;       \
                      (arr)[wbase + 128 + lane] = v2; (arr)[wbase + 192 + lane] = v3; }
  #define LDVG(arr) { v0 = (arr)[wbase + lane]; v1 = (arr)[wbase + 64 + lane];       \
                      v2 = (arr)[wbase + 128 + lane]; v3 = (arr)[wbase + 192 + lane]; }
  #define MCROSS(arr, J) { for (int i = (tid & 255); i < 1024; i += 256) {           \
      int l2 = i ^ (J); if (l2 > i) { ull a = (arr)[i], c = (arr)[l2];               \
        if (a < c) { (arr)[i] = c; (arr)[l2] = a; } } } }

  if (act) {
    #define PMAX(vm, mo) { int l_ = wbase + (mo) + lane;                             \
        ull a = ks[g2 * 2048 + l_]; ull c = ks[g2 * 2048 + 1024 + (1023 - l_)];      \
        vm = (a > c) ? a : c; }
    PMAX(v0, 0) PMAX(v1, 64) PMAX(v2, 128) PMAX(v3, 192)
    #undef PMAX
    STVG(ksh[g2]);
  }
  __syncthreads();
  if (act) MCROSS(ksh[g2], 512);
  __syncthreads();
  if (act) MCROSS(ksh[g2], 256);
  __syncthreads();
  if (act) { LDVG(ksh[g2]); LOCALPHASES(128, 2048); STVG(ksh[g2]); }
  __syncthreads();

  if (g2 == 0) {                    // tid < 256
    #define PMAX2(vm, mo) { int l_ = wbase + (mo) + lane;                            \
        ull a = ksh[0][l_]; ull c = ksh[1][1023 - l_]; vm = (a > c) ? a : c; }
    PMAX2(v0, 0) PMAX2(v1, 64) PMAX2(v2, 128) PMAX2(v3, 192)
    #undef PMAX2
  }
  __syncthreads();
  if (g2 == 0) STVG(ksh[0]);
  __syncthreads();
  if (tid < 256) MCROSS(ksh[0], 512);
  __syncthreads();
  if (tid < 256) MCROSS(ksh[0], 256);
  __syncthreads();

  if (g2 == 0) {
    LDVG(ksh[0]); LOCALPHASES(128, 2048);
    float fimg = getimg(img_i);
    float offs = fimg + 1.0f;
    emit_one(v0, wbase + lane,       b, N, boxes, labels, fimg, offs, ws_sorted, obox, area);
    emit_one(v1, wbase + 64 + lane,  b, N, boxes, labels, fimg, offs, ws_sorted, obox, area);
    emit_one(v2, wbase + 128 + lane, b, N, boxes, labels, fimg, offs, ws_sorted, obox, area);
    emit_one(v3, wbase + 192 + lane, b, N, boxes, labels, fimg, offs, ws_sorted, obox, area);
  }
  if (tid == 0) {
    ws_V[b] = cnt[0] + cnt[1] + cnt[2] + cnt[3];
    ws_done[b] = 0;
  }
  #undef STVG
  #undef LDVG
  #undef MCROSS
}

// =================== T: transposed suppression words for chunk 0 (w<16, j<1024) ===================
__global__ __launch_bounds__(256)
void suptr0(const float4* __restrict__ obox,
            const float*  __restrict__ area,
            const float*  __restrict__ nms_th,
            const int*    __restrict__ ws_V,
            ull* __restrict__ trans)
{
  __shared__ float4 rbox[64];
  __shared__ float  rarea[64];
  __shared__ ull    part[4][64];
  const int b = blockIdx.y;
  int rem = blockIdx.x, d = 0;
  while (rem >= d + 1) { rem -= d + 1; ++d; }
  const int jt = d, w = rem;        // jt in [0,16), w <= jt
  const int V = ws_V[b];
  if (jt * 64 >= V) return;
  const int JW = (V + 63) >> 6;
  if (w >= JW) return;

  const int tid = threadIdx.x, wave = tid >> 6, lane = tid & 63;
  double xt = (double)(*nms_th);
  float  th = (float)(1.0 / (1.0 + exp(-xt)));
  const float4* ob = obox + (size_t)b * NBOX;
  const float*  ar = area + (size_t)b * NBOX;

  if (tid < 64) { rbox[tid] = ob[w * 64 + tid]; rarea[tid] = ar[w * 64 + tid]; }
  __syncthreads();

  const int j = jt * 64 + lane;
  const float4 bj = ob[j];
  const float  aj = ar[j];
  ull p = 0;
  #pragma unroll 4
  for (int rr = 0; rr < 16; ++rr) {
    const int r = wave * 16 + rr;
    const int i = w * 64 + r;
    const float4 bi = rbox[r];
    const float  ai = rarea[r];
    float xx1 = fmaxf(bi.x, bj.x);
    float yy1 = fmaxf(bi.y, bj.y);
    float xx2 = fminf(bi.z, bj.z);
    float yy2 = fminf(bi.w, bj.w);
    float inter = fmaxf(xx2 - xx1, 0.0f) * fmaxf(yy2 - yy1, 0.0f);
    float denom = ai + aj;           // ((areas[i]+areas[j]) - inter) + 1e-9, ref order
    denom = denom - inter;
    denom = denom + 1e-9f;
    float iou = inter / denom;
    bool cond = (iou > th) && (j > i);
    p |= cond ? (1ull << r) : 0ull;
  }
  part[wave][lane] = p;
  __syncthreads();
  if (tid < 64)
    trans[(size_t)b * 16 * NBOX + (size_t)w * NBOX + jt * 64 + tid] =
        (part[0][tid] | part[1][tid]) | (part[2][tid] | part[3][tid]);
}

// =================== R0: Jacobi resolve chunk 0, 1-barrier iterations + fused output ===================
__global__ __launch_bounds__(NTHR)
void resolve0(const float* __restrict__ boxes,
              const float* __restrict__ scores,
              const int*   __restrict__ labels,
              const int*   __restrict__ img_i,
              const int*   __restrict__ ws_V,
              const ull*   __restrict__ trans,
              int* __restrict__ ws_done,
              int* __restrict__ ws_total,
              ull* __restrict__ ws_keptw,
              int* __restrict__ ws_K,
              const int* __restrict__ ws_sorted,
              float* __restrict__ out,
              int B, int N)
{
  __shared__ ull awb[2][16];
  __shared__ ull kw[16];
  __shared__ int kept_sh[MAXDET];
  __shared__ int fin, Ktot;

  const int b = blockIdx.x;
  const int tid = threadIdx.x, wave = tid >> 6, lane = tid & 63;
  const int V = ws_V[b], JW = (V + 63) >> 6;
  const int j = tid;
  const ull* tb = trans + (size_t)b * 16 * NBOX;

  ull supT[16];
  #pragma unroll
  for (int w = 0; w < 16; ++w)
    supT[w] = (w <= wave) ? tb[(size_t)w * NBOX + j] : 0ull;

  const bool a0 = (j < V);
  { ull bw0 = __ballot(a0); if (lane == 0) awb[0][wave] = bw0; }
  __syncthreads();

  // Jacobi fixpoint, single fused barrier per iteration
  int cur = 0;
  for (;;) {
    ull s = 0;
    #pragma unroll
    for (int w = 0; w < 16; ++w) s |= awb[cur][w] & supT[w];
    const bool keep = a0 && (s == 0ull);
    const ull bw = __ballot(keep);
    const bool mych = (lane == 0) && (bw != awb[cur][wave]);
    if (lane == 0) awb[cur ^ 1][wave] = bw;
    const int changed = __syncthreads_or((int)mych);
    if (!changed) break;
    cur ^= 1;
  }
  // converged: awb[cur] == awb[cur^1]

  if (wave == 0) {
    ull w64 = (lane < 16) ? awb[cur][lane] : 0ull;
    int pc = __popcll(w64), incl = pc;
    #pragma unroll
    for (int s2 = 1; s2 < 64; s2 <<= 1) { int v = __shfl_up(incl, s2); if (lane >= s2) incl += v; }
    const int totalALL = __shfl(incl, 63);
    const bool fi = (totalALL >= MAXDET) || (16 >= JW);
    if (fi) {
      int cumprev = incl - pc;
      int room = MAXDET - cumprev; if (room < 0) room = 0;
      int nk = (room < pc) ? room : pc;
      if (nk == 0) w64 = 0;
      else while (pc > nk) { int msb = 63 - __builtin_clzll(w64); w64 &= ~(1ull << msb); --pc; }
    }
    if (lane < 16) { kw[lane] = w64; ws_keptw[(size_t)b * 64 + lane] = w64; }
    if (lane == 0) { fin = fi ? 1 : 0; Ktot = (totalALL < MAXDET) ? totalALL : MAXDET; }
  }
  __syncthreads();

  if (!fin) { if (tid == 0) ws_total[b] = Ktot; return; }

  if (wave == 0) {
    ull km = (lane < 16) ? kw[lane] : 0ull;
    int pc = __popcll(km), incl = pc;
    #pragma unroll
    for (int s2 = 1; s2 < 64; s2 <<= 1) { int v = __shfl_up(incl, s2); if (lane >= s2) incl += v; }
    int base = incl - pc;
    while (km) { int l = __builtin_ctzll(km); km &= km - 1; kept_sh[base++] = lane * 64 + l; }
  }
  __syncthreads();

  const int K = Ktot;
  float fimg = getimg(img_i);
  const float* bx = boxes  + (size_t)b * N * 4;
  const float* sc = scores + (size_t)b * N;
  const int*   lb = labels + (size_t)b * N;
  const int*   so = ws_sorted + (size_t)b * N;
  float4* obx = (float4*)out;
  float*  osc = out + (size_t)B * MAXDET * 4;
  float*  olb = osc + (size_t)B * MAXDET;
  float*  ovl = olb + (size_t)B * MAXDET;
  for (int rI = tid; rI < MAXDET; rI += NTHR) {
    size_t slot = (size_t)b * MAXDET + rI;
    if (rI < K) {
      int i    = kept_sh[rI];
      int orig = so[i];
      float4 bb = ((const float4*)bx)[orig];
      bb.x = clipf(bb.x, fimg);
      bb.y = clipf(bb.y, fimg);
      bb.z = clipf(bb.z, fimg);
      bb.w = clipf(bb.w, fimg);
      obx[slot] = bb;
      osc[slot] = sc[orig];
      olb[slot] = (float)lb[orig];
      ovl[slot] = 1.0f;
    } else {
      obx[slot] = make_float4(0.f, 0.f, 0.f, 0.f);
      osc[slot] = 0.0f;
      olb[slot] = 0.0f;
      ovl[slot] = 0.0f;
    }
  }
  if (tid == 0) { ws_K[b] = K; ws_done[b] = 1; }
}

// =================== C: rare-path cleanup — full merge + chunks 1..3 + outputs ===================
__global__ __launch_bounds__(NTHR)
void cleanup_kernel(const ull* __restrict__ ws_keys,
                    const float* __restrict__ boxes,
                    const float* __restrict__ scores,
                    const int*   __restrict__ labels,
                    const int*   __restrict__ img_i,
                    const float* __restrict__ nms_th,
                    const int* __restrict__ ws_V,
                    int* __restrict__ ws_done,
                    const int* __restrict__ ws_total,
                    const ull* __restrict__ ws_keptw,
                    const float4* __restrict__ obox,
                    int* __restrict__ ws_K,
                    float* __restrict__ out,
                    int B, int N)
{
  __shared__ ull    K[4096];
  __shared__ float4 rb[1024];
  __shared__ float  ra[1024];
  __shared__ float4 kbox[MAXDET];
  __shared__ float  karea[MAXDET];
  __shared__ ull    aw[16];
  __shared__ ull    kw[64];
  __shared__ int    kept_sh[MAXDET];
  __shared__ int    flag, fin, Ktot;

  const int b = blockIdx.x;
  if (ws_done[b]) return;           // common case: ~free
  const int tid = threadIdx.x, wave = tid >> 6, lane = tid & 63;
  const int V = ws_V[b], JW = (V + 63) >> 6;
  float fimg = getimg(img_i);
  float offs = fimg + 1.0f;
  double xt = (double)(*nms_th);
  float th = (float)(1.0 / (1.0 + exp(-xt)));

  const ull* kb = ws_keys + (size_t)b * NBOX;
  for (int i = tid; i < 4096; i += NTHR) K[i] = kb[i];
  __syncthreads();
  { int i = tid;
    { ull a = K[i], c = K[2047 - i];        if (a < c) { K[i] = c; K[2047 - i] = a; } }
    { ull a = K[2048 + i], c = K[4095 - i]; if (a < c) { K[2048 + i] = c; K[4095 - i] = a; } } }
  __syncthreads();
  for (int j2 = 512; j2 >= 1; j2 >>= 1) {
    for (int idx = tid; idx < 4096; idx += NTHR) {
      int l = idx ^ j2;
      if (l > idx) { ull a = K[idx], c = K[l]; if (a < c) { K[idx] = c; K[l] = a; } } }
    __syncthreads(); }
  for (int m = 0; m < 2; ++m) {
    int i2 = tid + m * NTHR;
    ull a = K[i2], c = K[4095 - i2];
    if (a < c) { K[i2] = c; K[4095 - i2] = a; } }
  __syncthreads();
  for (int j2 = 1024; j2 >= 1; j2 >>= 1) {
    for (int idx = tid; idx < 4096; idx += NTHR) {
      int l = idx ^ j2;
      if (l > idx) { ull a = K[idx], c = K[l]; if (a < c) { K[idx] = c; K[l] = a; } } }
    __syncthreads(); }

  int total = ws_total[b];
  const ull* kwg = ws_keptw + (size_t)b * 64;
  if (tid < 64) kw[tid] = (tid < 16) ? kwg[tid] : 0ull;
  __syncthreads();
  if (wave == 0) {
    ull km = (lane < 16) ? kw[lane] : 0ull;
    int pc = __popcll(km), incl = pc;
    #pragma unroll
    for (int s2 = 1; s2 < 64; s2 <<= 1) { int v = __shfl_up(incl, s2); if (lane >= s2) incl += v; }
    int base = incl - pc;
    while (km) { int l = __builtin_ctzll(km); km &= km - 1; kept_sh[base++] = lane * 64 + l; }
  }
  __syncthreads();
  for (int k = tid; k < total; k += NTHR) {
    float4 bb = obox[(size_t)b * NBOX + kept_sh[k]];
    kbox[k]  = bb;
    karea[k] = fmaxf(bb.z - bb.x, 0.0f) * fmaxf(bb.w - bb.y, 0.0f);
  }
  __syncthreads();

  for (int c = 1; c < 4; ++c) {
    const int t0 = 16 * c, t1 = t0 + 16;
    {
      int gi = t0 * 64 + tid;
      unsigned orig = 0xFFFFFFFFu - (unsigned)(K[gi] & 0xFFFFFFFFull);
      float4 bb = ((const float4*)(boxes + (size_t)b * N * 4))[orig];
      float off = (float)labels[(size_t)b * N + orig] * offs;
      bb.x = clipf(bb.x, fimg) + off;
      bb.y = clipf(bb.y, fimg) + off;
      bb.z = clipf(bb.z, fimg) + off;
      bb.w = clipf(bb.w, fimg) + off;
      rb[tid] = bb;
      ra[tid] = fmaxf(bb.z - bb.x, 0.0f) * fmaxf(bb.w - bb.y, 0.0f);
    }
    __syncthreads();

    const int j = t0 * 64 + tid;
    const float4 bj = rb[tid];
    const float  aj = ra[tid];

    ull supT[16];
    for (int w = 0; w < 16; ++w) {
      ull word = 0;
      if (w <= wave) {
        for (int rr = 0; rr < 64; ++rr) {
          const int lr = w * 64 + rr;
          const float4 bi = rb[lr];
          const float  ai = ra[lr];
          float xx1 = fmaxf(bi.x, bj.x);
          float yy1 = fmaxf(bi.y, bj.y);
          float xx2 = fminf(bi.z, bj.z);
          float yy2 = fminf(bi.w, bj.w);
          float inter = fmaxf(xx2 - xx1, 0.0f) * fmaxf(yy2 - yy1, 0.0f);
          float denom = ai + aj;
          denom = denom - inter;
          denom = denom + 1e-9f;
          float iou = inter / denom;
          bool cond = (iou > th) && (tid > lr);
          word |= cond ? (1ull << rr) : 0ull;
        }
      }
      supT[w] = word;
    }
    bool cat = false;
    for (int k = 0; k < total && !cat; ++k) {
      const float4 bi = kbox[k];
      const float  ai = karea[k];
      float xx1 = fmaxf(bi.x, bj.x);
      float yy1 = fmaxf(bi.y, bj.y);
      float xx2 = fminf(bi.z, bj.z);
      float yy2 = fminf(bi.w, bj.w);
      float inter = fmaxf(xx2 - xx1, 0.0f) * fmaxf(yy2 - yy1, 0.0f);
      float denom = ai + aj;
      denom = denom - inter;
      denom = denom + 1e-9f;
      float iou = inter / denom;
      if (iou > th) cat = true;
    }
    const bool a0 = (j < V) && !cat;
    { ull bw0 = __ballot(a0); if (lane == 0) aw[wave] = bw0; }
    __syncthreads();

    for (;;) {
      ull s = 0;
      #pragma unroll
      for (int w = 0; w < 16; ++w) s |= aw[w] & supT[w];
      const bool keep = a0 && (s == 0ull);
      const ull bw = __ballot(keep);
      const bool diff = (lane == 0) && (bw != aw[wave]);
      __syncthreads();
      if (tid == 0) flag = 0;
      __syncthreads();
      if (diff) { aw[wave] = bw; flag = 1; }
      __syncthreads();
      if (!flag) break;
    }

    if (wave == 0) {
      ull w64 = (lane < 16) ? aw[lane] : 0ull;
      int pc = __popcll(w64), incl = pc;
      #pragma unroll
      for (int s2 = 1; s2 < 64; s2 <<= 1) { int v = __shfl_up(incl, s2); if (lane >= s2) incl += v; }
      const int totalALL = total + __shfl(incl, 63);
      const bool fi = (totalALL >= MAXDET) || (t1 >= JW);
      if (fi) {
        int cumprev = total + incl - pc;
        int room = MAXDET - cumprev; if (room < 0) room = 0;
        int nk = (room < pc) ? room : pc;
        if (nk == 0) { w64 = 0; pc = 0; }
        else while (pc > nk) { int msb = 63 - __builtin_clzll(w64); w64 &= ~(1ull << msb); --pc; }
      }
      if (lane < 16) kw[t0 + lane] = w64;
      if (lane == 0) { fin = fi ? 1 : 0; Ktot = (totalALL < MAXDET) ? totalALL : MAXDET; }
    }
    __syncthreads();

    if (wave == 0) {
      ull km = (lane < 16) ? kw[t0 + lane] : 0ull;
      int pc = __popcll(km), incl = pc;
      #pragma unroll
      for (int s2 = 1; s2 < 64; s2 <<= 1) { int v = __shfl_up(incl, s2); if (lane >= s2) incl += v; }
      int base = total + incl - pc;
      while (km) { int l = __builtin_ctzll(km); km &= km - 1; kept_sh[base++] = (t0 + lane) * 64 + l; }
    }
    __syncthreads();
    const int newtotal = Ktot;
    for (int k = total + tid; k < newtotal; k += NTHR) {
      int lr = kept_sh[k] - t0 * 64;
      kbox[k]  = rb[lr];
      karea[k] = ra[lr];
    }
    total = newtotal;
    __syncthreads();
    if (fin) break;
  }

  const int Kf = total;
  const float* bx = boxes  + (size_t)b * N * 4;
  const float* sc = scores + (size_t)b * N;
  const int*   lb = labels + (size_t)b * N;
  float4* obx = (float4*)out;
  float*  osc = out + (size_t)B * MAXDET * 4;
  float*  olb = osc + (size_t)B * MAXDET;
  float*  ovl = olb + (size_t)B * MAXDET;
  for (int rI = tid; rI < MAXDET; rI += NTHR) {
    size_t slot = (size_t)b * MAXDET + rI;
    if (rI < Kf) {
      int i = kept_sh[rI];
      unsigned orig = 0xFFFFFFFFu - (unsigned)(K[i] & 0xFFFFFFFFull);
      float4 bb = ((const float4*)bx)[orig];
      bb.x = clipf(bb.x, fimg);
      bb.y = clipf(bb.y, fimg);
      bb.z = clipf(bb.z, fimg);
      bb.w = clipf(bb.w, fimg);
      obx[slot] = bb;
      osc[slot] = sc[orig];
      olb[slot] = (float)lb[orig];
      ovl[slot] = 1.0f;
    } else {
      obx[slot] = make_float4(0.f, 0.f, 0.f, 0.f);
      osc[slot] = 0.0f;
      olb[slot] = 0.0f;
      ovl[slot] = 0.0f;
    }
  }
  if (tid == 0) { ws_K[b] = Kf; ws_done[b] = 1; }
}

// =================== R1: full 4-way merge (fallback path only) ===================
__global__ __launch_bounds__(NTHR)
void merge_full(const ull* __restrict__ ws_keys,
                const float* __restrict__ boxes,
                const int*   __restrict__ labels,
                const int*   __restrict__ img_i,
                int*    __restrict__ ws_sorted,
                float4* __restrict__ obox,
                float*  __restrict__ area,
                int N)
{
  __shared__ ull K[4096];
  const int b = blockIdx.x;
  const int tid = threadIdx.x;
  const ull* kb = ws_keys + (size_t)b * NBOX;
  for (int i = tid; i < 4096; i += NTHR) K[i] = kb[i];
  __syncthreads();
  { int i = tid;
    { ull a = K[i], c = K[2047 - i];        if (a < c) { K[i] = c; K[2047 - i] = a; } }
    { ull a = K[2048 + i], c = K[4095 - i]; if (a < c) { K[2048 + i] = c; K[4095 - i] = a; } } }
  __syncthreads();
  for (int j = 512; j >= 1; j >>= 1) {
    for (int idx = tid; idx < 4096; idx += NTHR) {
      int l = idx ^ j;
      if (l > idx) { ull a = K[idx], c = K[l]; if (a < c) { K[idx] = c; K[l] = a; } } }
    __syncthreads(); }
  for (int m = 0; m < 2; ++m) {
    int i2 = tid + m * 1024;
    ull a = K[i2], c = K[4095 - i2];
    if (a < c) { K[i2] = c; K[4095 - i2] = a; } }
  __syncthreads();
  for (int j = 1024; j >= 1; j >>= 1) {
    for (int idx = tid; idx < 4096; idx += NTHR) {
      int l = idx ^ j;
      if (l > idx) { ull a = K[idx], c = K[l]; if (a < c) { K[idx] = c; K[l] = a; } } }
    __syncthreads(); }

  float fimg = getimg(img_i);
  float offs = fimg + 1.0f;
  for (int idx = 1024 + tid; idx < 4096; idx += NTHR)
    emit_one(K[idx], idx, b, N, boxes, labels, fimg, offs, ws_sorted, obox, area);
}

// =================== fallback kernel (round-2 path, used if ws too small) ===================
struct SMB {
  float4       obox[CAP];
  unsigned int keepw[NWORDS];
  int          kept_pos[MAXDET];
  int          scal[4];
};

__global__ __launch_bounds__(NTHR)
void nms_kernel(const float* __restrict__ boxes,
                const float* __restrict__ scores,
                const int*   __restrict__ labels,
                const float* __restrict__ nms_th,
                const float* __restrict__ cls_w,
                const int*   __restrict__ img_i,
                float* __restrict__ out,
                int B, int N,
                const int* __restrict__ ws_sorted,
                const int* __restrict__ ws_V,
                float4* __restrict__ ws_ovf)
{
  __shared__ SMB sm;
  const int b    = blockIdx.x;
  const int tid  = threadIdx.x;

  const float* bx = boxes  + (size_t)b * N * 4;
  const float* sc = scores + (size_t)b * N;
  const int*   lb = labels + (size_t)b * N;
  const int*   so = ws_sorted + (size_t)b * N;

  float fimg = getimg(img_i);
  float off_scale = fimg + 1.0f;
  double xt = (double)(*nms_th);
  float  th = (float)(1.0 / (1.0 + exp(-xt)));

  const int V = ws_V[b];
  if (tid < 4) sm.scal[tid] = 0;

  for (int m = 0; m < 4; ++m) {
    int i = tid + m * NTHR;
    int orig = so[i];
    float4 bb = ((const float4*)bx)[orig];
    float off = (float)lb[orig] * off_scale;
    bb.x = clipf(bb.x, fimg) + off;
    bb.y = clipf(bb.y, fimg) + off;
    bb.z = clipf(bb.z, fimg) + off;
    bb.w = clipf(bb.w, fimg) + off;
    if (i < CAP) sm.obox[i] = bb;
    else         ws_ovf[(size_t)b * (NBOX - CAP) + (i - CAP)] = bb;
  }
  for (int w = tid; w < NWORDS; w += NTHR) {
    int lo = w * 32;
    unsigned val;
    if      (V >= lo + 32) val = 0xFFFFFFFFu;
    else if (V <= lo)      val = 0u;
    else                   val = (1u << (V - lo)) - 1u;
    sm.keepw[w] = val;
  }
  __syncthreads();

  const int nt = (V + 63) >> 6;
  int TR = 0;
  for (int t = 0; t < nt; ++t) {
    if (tid < 64) {
      int i0 = t * 64;
      int me = i0 + tid;
      float4 bb = (me < CAP) ? sm.obox[me]
                             : ws_ovf[(size_t)b * (NBOX - CAP) + (me - CAP)];
      float arJ = fmaxf(bb.z - bb.x, 0.0f) * fmaxf(bb.w - bb.y, 0.0f);
      ull supby = 0;
      for (int l = 0; l < 64; ++l) {
        int i = i0 + l;
        float4 bi = (i < CAP) ? sm.obox[i]
                              : ws_ovf[(size_t)b * (NBOX - CAP) + (i - CAP)];
        float ai = fmaxf(bi.z - bi.x, 0.0f) * fmaxf(bi.w - bi.y, 0.0f);
        float xx1 = fmaxf(bi.x, bb.x);
        float yy1 = fmaxf(bi.y, bb.y);
        float xx2 = fminf(bi.z, bb.z);
        float yy2 = fminf(bi.w, bb.w);
        float inter = fmaxf(xx2 - xx1, 0.0f) * fmaxf(yy2 - yy1, 0.0f);
        float denom = ai + arJ;
        denom = denom - inter;
        denom = denom + 1e-9f;
        float iou = inter / denom;
        if (iou > th) supby |= (1ull << l);
      }
      ull alive = ((ull)sm.keepw[2 * t + 1] << 32) | sm.keepw[2 * t];
      ull rem = alive;
      while (rem) {
        int l = __builtin_ctzll(rem);
        rem &= rem - 1;
        ull sup = __ballot((supby >> l) & 1ull);
        sup &= ((~1ull) << l);
        sup &= alive;
        alive &= ~sup;
        rem   &= ~sup;
      }
      if (tid == 0) {
        sm.keepw[2 * t]     = (unsigned)alive;
        sm.keepw[2 * t + 1] = (unsigned)(alive >> 32);
        atomicAdd(&sm.scal[1], __builtin_popcountll(alive));
      }
    }
    __syncthreads();
    TR = t + 1;
    if (sm.scal[1] >= MAXDET) break;

    int jstart = (t + 1) * 64;
    if (jstart < V) {
      ull alive = ((ull)sm.keepw[2 * t + 1] << 32) | sm.keepw[2 * t];
      if (alive) {
        for (int j = jstart + tid; j < V; j += NTHR) {
          unsigned wj = sm.keepw[j >> 5];
          if (!((wj >> (j & 31)) & 1u)) continue;
          float4 bj = (j < CAP) ? sm.obox[j]
                                : ws_ovf[(size_t)b * (NBOX - CAP) + (j - CAP)];
          float aj = fmaxf(bj.z - bj.x, 0.0f) * fmaxf(bj.w - bj.y, 0.0f);
          ull rem = alive;
          bool suppressed = false;
          while (rem) {
            int l = __builtin_ctzll(rem);
            rem &= rem - 1;
            int i = t * 64 + l;
            float4 bi = (i < CAP) ? sm.obox[i]
                                  : ws_ovf[(size_t)b * (NBOX - CAP) + (i - CAP)];
            float ai = fmaxf(bi.z - bi.x, 0.0f) * fmaxf(bi.w - bi.y, 0.0f);
            float xx1 = fmaxf(bi.x, bj.x);
            float yy1 = fmaxf(bi.y, bj.y);
            float xx2 = fminf(bi.z, bj.z);
            float yy2 = fminf(bi.w, bj.w);
            float inter = fmaxf(xx2 - xx1, 0.0f) * fmaxf(yy2 - yy1, 0.0f);
            float denom = ai + aj;
            denom = denom - inter;
            denom = denom + 1e-9f;
            float iou = inter / denom;
            if (iou > th) { suppressed = true; break; }
          }
          if (suppressed) atomicAnd(&sm.keepw[j >> 5], ~(1u << (j & 31)));
        }
      }
    }
    __syncthreads();
  }

  if (tid < NWORDS && tid >= TR * 2) sm.keepw[tid] = 0;
  __syncthreads();
  if (tid == 0) {
    int r = 0;
    for (int w = 0; w < NWORDS && r < MAXDET; ++w) {
      unsigned bits = sm.keepw[w];
      while (bits && r < MAXDET) {
        int l = __builtin_ctz(bits);
        bits &= bits - 1;
        sm.kept_pos[r++] = w * 32 + l;
      }
    }
    sm.scal[3] = r;
  }
  __syncthreads();
  const int K = sm.scal[3];

  float4* obx = (float4*)out;
  float*  osc = out + (size_t)B * MAXDET * 4;
  float*  olb = osc + (size_t)B * MAXDET;
  float*  ovl = olb + (size_t)B * MAXDET;
  for (int r = tid; r < MAXDET; r += NTHR) {
    size_t slot = (size_t)b * MAXDET + r;
    if (r < K) {
      int i    = sm.kept_pos[r];
      int orig = so[i];
      float4 bb = ((const float4*)bx)[orig];
      bb.x = clipf(bb.x, fimg);
      bb.y = clipf(bb.y, fimg);
      bb.z = clipf(bb.z, fimg);
      bb.w = clipf(bb.w, fimg);
      obx[slot] = bb;
      osc[slot] = sc[orig];
      olb[slot] = (float)lb[orig];
      ovl[slot] = 1.0f;
    } else {
      obx[slot] = make_float4(0.f, 0.f, 0.f, 0.f);
      osc[slot] = 0.0f;
      olb[slot] = 0.0f;
      ovl[slot] = 0.0f;
    }
  }
}

extern "C" void kernel_launch(void* const* d_in, const int* in_sizes, int n_in,
                              void* d_out, int out_size, void* d_ws, size_t ws_size,
                              hipStream_t stream) {
  const float* boxes      = (const float*)d_in[0];
  const float* scores     = (const float*)d_in[1];
  const int*   labels     = (const int*)d_in[2];
  const float* nms_thresh = (const float*)d_in[3];
  const float* cls_w      = (const float*)d_in[4];
  const int*   img_sz     = (const int*)d_in[5];

  int B = out_size / (MAXDET * 7);
  int N = in_sizes[1] / B;               // 4096

  // ws layout
  size_t off_sorted = 0;
  size_t off_V      = (off_sorted + (size_t)B * N * 4 + 255) & ~(size_t)255;
  size_t off_done   = off_V + (size_t)B * 4;
  size_t off_total  = off_done + (size_t)B * 4;
  size_t off_Kf     = off_total + (size_t)B * 4;
  size_t off_kw     = (off_Kf + (size_t)B * 4 + 255) & ~(size_t)255;
  size_t off_obox   = (off_kw + (size_t)B * 64 * 8 + 255) & ~(size_t)255;
  size_t off_area   = off_obox + (size_t)B * NBOX * 16;
  size_t off_keys   = (off_area + (size_t)B * NBOX * 4 + 255) & ~(size_t)255;
  size_t off_tr     = (off_keys + (size_t)B * NBOX * 8 + 255) & ~(size_t)255;
  size_t sz_tr      = (size_t)B * 16 * NBOX * 8;   // 8 MiB at B=16
  size_t need_fast  = off_tr + sz_tr;

  int*    ws_sorted = (int*)((char*)d_ws + off_sorted);
  int*    ws_V      = (int*)((char*)d_ws + off_V);
  int*    ws_done   = (int*)((char*)d_ws + off_done);
  int*    ws_total  = (int*)((char*)d_ws + off_total);
  int*    ws_K      = (int*)((char*)d_ws + off_Kf);
  ull*    ws_keptw  = (ull*)((char*)d_ws + off_kw);
  float4* obox      = (float4*)((char*)d_ws + off_obox);
  float*  area      = (float*)((char*)d_ws + off_area);
  ull*    ws_keys   = (ull*)((char*)d_ws + off_keys);
  ull*    trans     = (ull*)((char*)d_ws + off_tr);

  if (ws_size >= need_fast && N == NBOX) {
    sort_merge<<<dim3(B), dim3(NTHR), 0, stream>>>(
        scores, labels, cls_w, boxes, img_sz,
        ws_keys, ws_sorted, ws_V, ws_done, obox, area, N);
    suptr0<<<dim3(136, B), dim3(256), 0, stream>>>(
        obox, area, nms_thresh, ws_V, trans);
    resolve0<<<dim3(B), dim3(NTHR), 0, stream>>>(
        boxes, scores, labels, img_sz, ws_V, trans,
        ws_done, ws_total, ws_keptw, ws_K, ws_sorted, (float*)d_out, B, N);
    cleanup_kernel<<<dim3(B), dim3(NTHR), 0, stream>>>(
        ws_keys, boxes, scores, labels, img_sz, nms_thresh, ws_V,
        ws_done, ws_total, ws_keptw, obox, ws_K, (float*)d_out, B, N);
  } else {
    sort_merge<<<dim3(B), dim3(NTHR), 0, stream>>>(
        scores, labels, cls_w, boxes, img_sz,
        ws_keys, ws_sorted, ws_V, ws_done, obox, area, N);
    merge_full<<<dim3(B), dim3(NTHR), 0, stream>>>(
        ws_keys, boxes, labels, img_sz, ws_sorted, obox, area, N);
    float4* ws_ovf = (float4*)((char*)d_ws + off_keys);  // reuse keys tail region
    nms_kernel<<<dim3(B), dim3(NTHR), 0, stream>>>(boxes, scores, labels,
                                                   nms_thresh, cls_w, img_sz,
                                                   (float*)d_out, B, N,
                                                   ws_sorted, ws_V, ws_ovf);
  }
}

// Round 16
// 59.851 us; speedup vs baseline: 1.0447x; 1.0447x over previous
//
#include <hip/hip_runtime.h>
#include <math.h>

#define NBOX   4096
#define NTHR   1024
#define MAXDET 300
#define CAP    3968          // fallback path
#define NWORDS (NBOX / 32)

typedef unsigned long long ull;

__device__ __forceinline__ float clipf(float v, float hi) {
  return fminf(fmaxf(v, 0.0f), hi);
}

__device__ __forceinline__ float getimg(const int* img_i) {
  int iv = *img_i;
  return (iv > 0 && iv < (1 << 24)) ? (float)iv : __int_as_float(iv);
}

// comparator macros: "up" (e&K)==0 => descending run (matches argsort(-key))
#define CSWAP_REG(va, vb, eo, K) { int e_ = wbase + (eo) + lane;                     \
    if ((((e_) & (K)) == 0) ? ((va) < (vb)) : ((va) > (vb))) { ull t_=(va); (va)=(vb); (vb)=t_; } }
#define CSWAP_SHFL(vr, eo, K) { int e_ = wbase + (eo) + lane;                        \
    ull c_ = __shfl_xor((vr), j);                                                    \
    bool km_ = ((((e_) & (K)) == 0) == ((lane & j) == 0));                           \
    (vr) = km_ ? ((vr) > c_ ? (vr) : c_) : ((vr) < c_ ? (vr) : c_); }
#define LOCALPHASES(jmax, K) { for (int j = (jmax); j >= 1; j >>= 1) {               \
    if (j == 128)      { CSWAP_REG(v0, v2, 0, K);  CSWAP_REG(v1, v3, 64, K);  }      \
    else if (j == 64)  { CSWAP_REG(v0, v1, 0, K);  CSWAP_REG(v2, v3, 128, K); }      \
    else { CSWAP_SHFL(v0, 0, K); CSWAP_SHFL(v1, 64, K); CSWAP_SHFL(v2, 128, K); CSWAP_SHFL(v3, 192, K); } } }

__device__ __forceinline__ void emit_one(ull key, int l, int b, int N,
    const float* boxes, const int* labels, float fimg, float offs,
    int* ws_sorted, float4* obox, float* area)
{
  unsigned orig = 0xFFFFFFFFu - (unsigned)(key & 0xFFFFFFFFull);
  ws_sorted[(size_t)b * N + l] = (int)orig;
  const float4* bx4 = (const float4*)(boxes + (size_t)b * N * 4);
  float4 bb = bx4[orig];
  float off = (float)labels[(size_t)b * N + orig] * offs;
  bb.x = clipf(bb.x, fimg) + off;
  bb.y = clipf(bb.y, fimg) + off;
  bb.z = clipf(bb.z, fimg) + off;
  bb.w = clipf(bb.w, fimg) + off;
  obox[(size_t)b * NBOX + l] = bb;
  area[(size_t)b * NBOX + l] = fmaxf(bb.z - bb.x, 0.0f) * fmaxf(bb.w - bb.y, 0.0f);
}

// =================== S1: per-1024-segment key build + bitonic sort (descending) ===================
__global__ __launch_bounds__(256)
void sort_seg(const float* __restrict__ scores,
              const int*   __restrict__ labels,
              const float* __restrict__ cls_w,
              ull* __restrict__ ws_keys,
              int* __restrict__ ws_Vseg,
              int N)
{
  __shared__ ull ks[1024];
  __shared__ int cnt;
  const int b = blockIdx.y, s = blockIdx.x;
  const int tid = threadIdx.x, lane = tid & 63, wave = tid >> 6;
  const int wbase = wave * 256;
  const int base  = s * 1024;
  const float* sc = scores + (size_t)b * N;
  const int*   lb = labels + (size_t)b * N;
  if (tid == 0) cnt = 0;

  ull v0, v1, v2, v3;
  int vc = 0;
  #define BUILD(vm, mo) { int l_ = wbase + (mo) + lane; int gi = base + l_;          \
      float sv = sc[gi]; ull key = (ull)(0xFFFFFFFFu - (unsigned)gi);                \
      if (sv > 0.3f) { float w_ = sv * cls_w[lb[gi]]; unsigned ub = __float_as_uint(w_); \
        ub = (ub & 0x80000000u) ? ~ub : (ub | 0x80000000u);                          \
        key |= ((ull)ub << 32); ++vc; }                                              \
      vm = key; }
  BUILD(v0, 0) BUILD(v1, 64) BUILD(v2, 128) BUILD(v3, 192)
  #undef BUILD
  atomicAdd(&cnt, vc);

  for (int k2 = 2; k2 <= 256; k2 <<= 1) { LOCALPHASES(k2 >> 1, k2); }

  #define STV { ks[wbase + lane] = v0; ks[wbase + 64 + lane] = v1;                   \
                ks[wbase + 128 + lane] = v2; ks[wbase + 192 + lane] = v3; }
  #define LDV { v0 = ks[wbase + lane]; v1 = ks[wbase + 64 + lane];                   \
                v2 = ks[wbase + 128 + lane]; v3 = ks[wbase + 192 + lane]; }
  #define CROSS(J, K) { for (int i = tid; i < 1024; i += 256) { int l2 = i ^ (J);    \
      if (l2 > i) { ull a = ks[i], c = ks[l2];                                       \
        if ((((i) & (K)) == 0) ? (a < c) : (a > c)) { ks[i] = c; ks[l2] = a; } } } }

  STV; __syncthreads();
  CROSS(256, 512); __syncthreads();
  LDV; LOCALPHASES(128, 512);
  STV; __syncthreads();
  CROSS(512, 1024); __syncthreads();
  CROSS(256, 1024); __syncthreads();
  LDV; LOCALPHASES(128, 1024);

  ull* kb = ws_keys + (size_t)b * NBOX + base;
  kb[wbase + lane]       = v0;
  kb[wbase + 64 + lane]  = v1;
  kb[wbase + 128 + lane] = v2;
  kb[wbase + 192 + lane] = v3;
  __syncthreads();
  if (tid == 0) ws_Vseg[b * 4 + s] = cnt;
  #undef STV
  #undef LDV
  #undef CROSS
}

// =================== M: tournament top-1024 merge + fused prep (ranks 0..1023) ===================
__global__ __launch_bounds__(512)
void merge_top(const ull* __restrict__ ws_keys,
               const int* __restrict__ ws_Vseg,
               const float* __restrict__ boxes,
               const int*   __restrict__ labels,
               const int*   __restrict__ img_i,
               int*    __restrict__ ws_sorted,
               int*    __restrict__ ws_V,
               int*    __restrict__ ws_done,
               float4* __restrict__ obox,
               float*  __restrict__ area,
               int N)
{
  __shared__ ull ksh[2][1024];
  const int b = blockIdx.x;
  const int tid = threadIdx.x, lane = tid & 63, wave = tid >> 6;
  const int g = wave >> 2, wv = wave & 3;
  const int wbase = wv * 256;
  const ull* kb = ws_keys + (size_t)b * NBOX;

  ull v0, v1, v2, v3;
  #define PMAX(vm, mo) { int l_ = wbase + (mo) + lane;                               \
      ull a = kb[g * 2048 + l_]; ull c = kb[g * 2048 + 1024 + (1023 - l_)];          \
      vm = (a > c) ? a : c; }
  PMAX(v0, 0) PMAX(v1, 64) PMAX(v2, 128) PMAX(v3, 192)
  #undef PMAX

  #define STVG(arr) { (arr)[wbase + lane] = v0; (arr)[wbase + 64 + lane] = v1;       \
                      (arr)[wbase + 128 + lane] = v2; (arr)[wbase + 192 + lane] = v3; }
  #define LDVG(arr) { v0 = (arr)[wbase + lane]; v1 = (arr)[wbase + 64 + lane];       \
                      v2 = (arr)[wbase + 128 + lane]; v3 = (arr)[wbase + 192 + lane]; }
  #define MCROSS(arr, J) { for (int i = (tid & 255); i < 1024; i += 256) {           \
      int l2 = i ^ (J); if (l2 > i) { ull a = (arr)[i], c = (arr)[l2];               \
        if (a < c) { (arr)[i] = c; (arr)[l2] = a; } } } }

  STVG(ksh[g]); __syncthreads();
  MCROSS(ksh[g], 512); __syncthreads();
  MCROSS(ksh[g], 256); __syncthreads();
  LDVG(ksh[g]); LOCALPHASES(128, 2048);
  STVG(ksh[g]); __syncthreads();

  if (g == 0) {
    #define PMAX2(vm, mo) { int l_ = wbase + (mo) + lane;                            \
        ull a = ksh[0][l_]; ull c = ksh[1][1023 - l_]; vm = (a > c) ? a : c; }
    PMAX2(v0, 0) PMAX2(v1, 64) PMAX2(v2, 128) PMAX2(v3, 192)
    #undef PMAX2
  }
  __syncthreads();
  if (g == 0) STVG(ksh[0]);
  __syncthreads();
  if (tid < 256) MCROSS(ksh[0], 512);
  __syncthreads();
  if (tid < 256) MCROSS(ksh[0], 256);
  __syncthreads();

  if (g == 0) {
    LDVG(ksh[0]); LOCALPHASES(128, 2048);
    float fimg = getimg(img_i);
    float offs = fimg + 1.0f;
    emit_one(v0, wbase + lane,       b, N, boxes, labels, fimg, offs, ws_sorted, obox, area);
    emit_one(v1, wbase + 64 + lane,  b, N, boxes, labels, fimg, offs, ws_sorted, obox, area);
    emit_one(v2, wbase + 128 + lane, b, N, boxes, labels, fimg, offs, ws_sorted, obox, area);
    emit_one(v3, wbase + 192 + lane, b, N, boxes, labels, fimg, offs, ws_sorted, obox, area);
  }
  if (tid == 0) {
    ws_V[b] = ws_Vseg[b * 4] + ws_Vseg[b * 4 + 1] + ws_Vseg[b * 4 + 2] + ws_Vseg[b * 4 + 3];
    ws_done[b] = 0;
  }
  #undef STVG
  #undef LDVG
  #undef MCROSS
}

// =================== T: transposed suppression words for chunk 0 (w<16, j<1024) ===================
__global__ __launch_bounds__(256)
void suptr0(const float4* __restrict__ obox,
            const float*  __restrict__ area,
            const float*  __restrict__ nms_th,
            const int*    __restrict__ ws_V,
            ull* __restrict__ trans)
{
  __shared__ float4 rbox[64];
  __shared__ float  rarea[64];
  __shared__ ull    part[4][64];
  const int b = blockIdx.y;
  int rem = blockIdx.x, d = 0;
  while (rem >= d + 1) { rem -= d + 1; ++d; }
  const int jt = d, w = rem;        // jt in [0,16), w <= jt
  const int V = ws_V[b];
  if (jt * 64 >= V) return;
  const int JW = (V + 63) >> 6;
  if (w >= JW) return;

  const int tid = threadIdx.x, wave = tid >> 6, lane = tid & 63;
  double xt = (double)(*nms_th);
  float  th = (float)(1.0 / (1.0 + exp(-xt)));
  const float4* ob = obox + (size_t)b * NBOX;
  const float*  ar = area + (size_t)b * NBOX;

  if (tid < 64) { rbox[tid] = ob[w * 64 + tid]; rarea[tid] = ar[w * 64 + tid]; }
  __syncthreads();

  const int j = jt * 64 + lane;
  const float4 bj = ob[j];
  const float  aj = ar[j];
  ull p = 0;
  #pragma unroll 4
  for (int rr = 0; rr < 16; ++rr) {
    const int r = wave * 16 + rr;
    const int i = w * 64 + r;
    const float4 bi = rbox[r];
    const float  ai = rarea[r];
    float xx1 = fmaxf(bi.x, bj.x);
    float yy1 = fmaxf(bi.y, bj.y);
    float xx2 = fminf(bi.z, bj.z);
    float yy2 = fminf(bi.w, bj.w);
    float inter = fmaxf(xx2 - xx1, 0.0f) * fmaxf(yy2 - yy1, 0.0f);
    float denom = ai + aj;           // ((areas[i]+areas[j]) - inter) + 1e-9, ref order
    denom = denom - inter;
    denom = denom + 1e-9f;
    float iou = inter / denom;
    bool cond = (iou > th) && (j > i);
    p |= cond ? (1ull << r) : 0ull;
  }
  part[wave][lane] = p;
  __syncthreads();
  if (tid < 64)
    trans[(size_t)b * 16 * NBOX + (size_t)w * NBOX + jt * 64 + tid] =
        (part[0][tid] | part[1][tid]) | (part[2][tid] | part[3][tid]);
}

// =================== R0: Jacobi resolve chunk 0, 1-barrier iterations + fused output ===================
__global__ __launch_bounds__(NTHR)
void resolve0(const float* __restrict__ boxes,
              const float* __restrict__ scores,
              const int*   __restrict__ labels,
              const int*   __restrict__ img_i,
              const int*   __restrict__ ws_V,
              const ull*   __restrict__ trans,
              int* __restrict__ ws_done,
              int* __restrict__ ws_total,
              ull* __restrict__ ws_keptw,
              int* __restrict__ ws_K,
              const int* __restrict__ ws_sorted,
              float* __restrict__ out,
              int B, int N)
{
  __shared__ ull awb[2][16];
  __shared__ ull kw[16];
  __shared__ int kept_sh[MAXDET];
  __shared__ int fin, Ktot;

  const int b = blockIdx.x;
  const int tid = threadIdx.x, wave = tid >> 6, lane = tid & 63;
  const int V = ws_V[b], JW = (V + 63) >> 6;
  const int j = tid;
  const ull* tb = trans + (size_t)b * 16 * NBOX;

  ull supT[16];
  #pragma unroll
  for (int w = 0; w < 16; ++w)
    supT[w] = (w <= wave) ? tb[(size_t)w * NBOX + j] : 0ull;

  const bool a0 = (j < V);
  { ull bw0 = __ballot(a0); if (lane == 0) awb[0][wave] = bw0; }
  __syncthreads();

  // Jacobi fixpoint, single fused barrier per iteration
  int cur = 0;
  for (;;) {
    ull s = 0;
    #pragma unroll
    for (int w = 0; w < 16; ++w) s |= awb[cur][w] & supT[w];
    const bool keep = a0 && (s == 0ull);
    const ull bw = __ballot(keep);
    const bool mych = (lane == 0) && (bw != awb[cur][wave]);
    if (lane == 0) awb[cur ^ 1][wave] = bw;
    const int changed = __syncthreads_or((int)mych);
    if (!changed) break;
    cur ^= 1;
  }

  if (wave == 0) {
    ull w64 = (lane < 16) ? awb[cur][lane] : 0ull;
    int pc = __popcll(w64), incl = pc;
    #pragma unroll
    for (int s2 = 1; s2 < 64; s2 <<= 1) { int v = __shfl_up(incl, s2); if (lane >= s2) incl += v; }
    const int totalALL = __shfl(incl, 63);
    const bool fi = (totalALL >= MAXDET) || (16 >= JW);
    if (fi) {
      int cumprev = incl - pc;
      int room = MAXDET - cumprev; if (room < 0) room = 0;
      int nk = (room < pc) ? room : pc;
      if (nk == 0) w64 = 0;
      else while (pc > nk) { int msb = 63 - __builtin_clzll(w64); w64 &= ~(1ull << msb); --pc; }
    }
    if (lane < 16) { kw[lane] = w64; ws_keptw[(size_t)b * 64 + lane] = w64; }
    if (lane == 0) { fin = fi ? 1 : 0; Ktot = (totalALL < MAXDET) ? totalALL : MAXDET; }
  }
  __syncthreads();

  if (!fin) { if (tid == 0) ws_total[b] = Ktot; return; }

  if (wave == 0) {
    ull km = (lane < 16) ? kw[lane] : 0ull;
    int pc = __popcll(km), incl = pc;
    #pragma unroll
    for (int s2 = 1; s2 < 64; s2 <<= 1) { int v = __shfl_up(incl, s2); if (lane >= s2) incl += v; }
    int base = incl - pc;
    while (km) { int l = __builtin_ctzll(km); km &= km - 1; kept_sh[base++] = lane * 64 + l; }
  }
  __syncthreads();

  const int K = Ktot;
  float fimg = getimg(img_i);
  const float* bx = boxes  + (size_t)b * N * 4;
  const float* sc = scores + (size_t)b * N;
  const int*   lb = labels + (size_t)b * N;
  const int*   so = ws_sorted + (size_t)b * N;
  float4* obx = (float4*)out;
  float*  osc = out + (size_t)B * MAXDET * 4;
  float*  olb = osc + (size_t)B * MAXDET;
  float*  ovl = olb + (size_t)B * MAXDET;
  for (int rI = tid; rI < MAXDET; rI += NTHR) {
    size_t slot = (size_t)b * MAXDET + rI;
    if (rI < K) {
      int i    = kept_sh[rI];
      int orig = so[i];
      float4 bb = ((const float4*)bx)[orig];
      bb.x = clipf(bb.x, fimg);
      bb.y = clipf(bb.y, fimg);
      bb.z = clipf(bb.z, fimg);
      bb.w = clipf(bb.w, fimg);
      obx[slot] = bb;
      osc[slot] = sc[orig];
      olb[slot] = (float)lb[orig];
      ovl[slot] = 1.0f;
    } else {
      obx[slot] = make_float4(0.f, 0.f, 0.f, 0.f);
      osc[slot] = 0.0f;
      olb[slot] = 0.0f;
      ovl[slot] = 0.0f;
    }
  }
  if (tid == 0) { ws_K[b] = K; ws_done[b] = 1; }
}

// =================== C: rare-path cleanup — full merge + chunks 1..3 + outputs ===================
__global__ __launch_bounds__(NTHR)
void cleanup_kernel(const ull* __restrict__ ws_keys,
                    const float* __restrict__ boxes,
                    const float* __restrict__ scores,
                    const int*   __restrict__ labels,
                    const int*   __restrict__ img_i,
                    const float* __restrict__ nms_th,
                    const int* __restrict__ ws_V,
                    int* __restrict__ ws_done,
                    const int* __restrict__ ws_total,
                    const ull* __restrict__ ws_keptw,
                    const float4* __restrict__ obox,
                    int* __restrict__ ws_K,
                    float* __restrict__ out,
                    int B, int N)
{
  __shared__ ull    K[4096];
  __shared__ float4 rb[1024];
  __shared__ float  ra[1024];
  __shared__ float4 kbox[MAXDET];
  __shared__ float  karea[MAXDET];
  __shared__ ull    aw[16];
  __shared__ ull    kw[64];
  __shared__ int    kept_sh[MAXDET];
  __shared__ int    flag, fin, Ktot;

  const int b = blockIdx.x;
  if (ws_done[b]) return;           // common case: ~free
  const int tid = threadIdx.x, wave = tid >> 6, lane = tid & 63;
  const int V = ws_V[b], JW = (V + 63) >> 6;
  float fimg = getimg(img_i);
  float offs = fimg + 1.0f;
  double xt = (double)(*nms_th);
  float th = (float)(1.0 / (1.0 + exp(-xt)));

  const ull* kb = ws_keys + (size_t)b * NBOX;
  for (int i = tid; i < 4096; i += NTHR) K[i] = kb[i];
  __syncthreads();
  { int i = tid;
    { ull a = K[i], c = K[2047 - i];        if (a < c) { K[i] = c; K[2047 - i] = a; } }
    { ull a = K[2048 + i], c = K[4095 - i]; if (a < c) { K[2048 + i] = c; K[4095 - i] = a; } } }
  __syncthreads();
  for (int j2 = 512; j2 >= 1; j2 >>= 1) {
    for (int idx = tid; idx < 4096; idx += NTHR) {
      int l = idx ^ j2;
      if (l > idx) { ull a = K[idx], c = K[l]; if (a < c) { K[idx] = c; K[l] = a; } } }
    __syncthreads(); }
  for (int m = 0; m < 2; ++m) {
    int i2 = tid + m * NTHR;
    ull a = K[i2], c = K[4095 - i2];
    if (a < c) { K[i2] = c; K[4095 - i2] = a; } }
  __syncthreads();
  for (int j2 = 1024; j2 >= 1; j2 >>= 1) {
    for (int idx = tid; idx < 4096; idx += NTHR) {
      int l = idx ^ j2;
      if (l > idx) { ull a = K[idx], c = K[l]; if (a < c) { K[idx] = c; K[l] = a; } } }
    __syncthreads(); }

  int total = ws_total[b];
  const ull* kwg = ws_keptw + (size_t)b * 64;
  if (tid < 64) kw[tid] = (tid < 16) ? kwg[tid] : 0ull;
  __syncthreads();
  if (wave == 0) {
    ull km = (lane < 16) ? kw[lane] : 0ull;
    int pc = __popcll(km), incl = pc;
    #pragma unroll
    for (int s2 = 1; s2 < 64; s2 <<= 1) { int v = __shfl_up(incl, s2); if (lane >= s2) incl += v; }
    int base = incl - pc;
    while (km) { int l = __builtin_ctzll(km); km &= km - 1; kept_sh[base++] = lane * 64 + l; }
  }
  __syncthreads();
  for (int k = tid; k < total; k += NTHR) {
    float4 bb = obox[(size_t)b * NBOX + kept_sh[k]];
    kbox[k]  = bb;
    karea[k] = fmaxf(bb.z - bb.x, 0.0f) * fmaxf(bb.w - bb.y, 0.0f);
  }
  __syncthreads();

  for (int c = 1; c < 4; ++c) {
    const int t0 = 16 * c, t1 = t0 + 16;
    {
      int gi = t0 * 64 + tid;
      unsigned orig = 0xFFFFFFFFu - (unsigned)(K[gi] & 0xFFFFFFFFull);
      float4 bb = ((const float4*)(boxes + (size_t)b * N * 4))[orig];
      float off = (float)labels[(size_t)b * N + orig] * offs;
      bb.x = clipf(bb.x, fimg) + off;
      bb.y = clipf(bb.y, fimg) + off;
      bb.z = clipf(bb.z, fimg) + off;
      bb.w = clipf(bb.w, fimg) + off;
      rb[tid] = bb;
      ra[tid] = fmaxf(bb.z - bb.x, 0.0f) * fmaxf(bb.w - bb.y, 0.0f);
    }
    __syncthreads();

    const int j = t0 * 64 + tid;
    const float4 bj = rb[tid];
    const float  aj = ra[tid];

    ull supT[16];
    for (int w = 0; w < 16; ++w) {
      ull word = 0;
      if (w <= wave) {
        for (int rr = 0; rr < 64; ++rr) {
          const int lr = w * 64 + rr;
          const float4 bi = rb[lr];
          const float  ai = ra[lr];
          float xx1 = fmaxf(bi.x, bj.x);
          float yy1 = fmaxf(bi.y, bj.y);
          float xx2 = fminf(bi.z, bj.z);
          float yy2 = fminf(bi.w, bj.w);
          float inter = fmaxf(xx2 - xx1, 0.0f) * fmaxf(yy2 - yy1, 0.0f);
          float denom = ai + aj;
          denom = denom - inter;
          denom = denom + 1e-9f;
          float iou = inter / denom;
          bool cond = (iou > th) && (tid > lr);
          word |= cond ? (1ull << rr) : 0ull;
        }
      }
      supT[w] = word;
    }
    bool cat = false;
    for (int k = 0; k < total && !cat; ++k) {
      const float4 bi = kbox[k];
      const float  ai = karea[k];
      float xx1 = fmaxf(bi.x, bj.x);
      float yy1 = fmaxf(bi.y, bj.y);
      float xx2 = fminf(bi.z, bj.z);
      float yy2 = fminf(bi.w, bj.w);
      float inter = fmaxf(xx2 - xx1, 0.0f) * fmaxf(yy2 - yy1, 0.0f);
      float denom = ai + aj;
      denom = denom - inter;
      denom = denom + 1e-9f;
      float iou = inter / denom;
      if (iou > th) cat = true;
    }
    const bool a0 = (j < V) && !cat;
    { ull bw0 = __ballot(a0); if (lane == 0) aw[wave] = bw0; }
    __syncthreads();

    for (;;) {
      ull s = 0;
      #pragma unroll
      for (int w = 0; w < 16; ++w) s |= aw[w] & supT[w];
      const bool keep = a0 && (s == 0ull);
      const ull bw = __ballot(keep);
      const bool diff = (lane == 0) && (bw != aw[wave]);
      __syncthreads();
      if (tid == 0) flag = 0;
      __syncthreads();
      if (diff) { aw[wave] = bw; flag = 1; }
      __syncthreads();
      if (!flag) break;
    }

    if (wave == 0) {
      ull w64 = (lane < 16) ? aw[lane] : 0ull;
      int pc = __popcll(w64), incl = pc;
      #pragma unroll
      for (int s2 = 1; s2 < 64; s2 <<= 1) { int v = __shfl_up(incl, s2); if (lane >= s2) incl += v; }
      const int totalALL = total + __shfl(incl, 63);
      const bool fi = (totalALL >= MAXDET) || (t1 >= JW);
      if (fi) {
        int cumprev = total + incl - pc;
        int room = MAXDET - cumprev; if (room < 0) room = 0;
        int nk = (room < pc) ? room : pc;
        if (nk == 0) { w64 = 0; pc = 0; }
        else while (pc > nk) { int msb = 63 - __builtin_clzll(w64); w64 &= ~(1ull << msb); --pc; }
      }
      if (lane < 16) kw[t0 + lane] = w64;
      if (lane == 0) { fin = fi ? 1 : 0; Ktot = (totalALL < MAXDET) ? totalALL : MAXDET; }
    }
    __syncthreads();

    if (wave == 0) {
      ull km = (lane < 16) ? kw[t0 + lane] : 0ull;
      int pc = __popcll(km), incl = pc;
      #pragma unroll
      for (int s2 = 1; s2 < 64; s2 <<= 1) { int v = __shfl_up(incl, s2); if (lane >= s2) incl += v; }
      int base = total + incl - pc;
      while (km) { int l = __builtin_ctzll(km); km &= km - 1; kept_sh[base++] = (t0 + lane) * 64 + l; }
    }
    __syncthreads();
    const int newtotal = Ktot;
    for (int k = total + tid; k < newtotal; k += NTHR) {
      int lr = kept_sh[k] - t0 * 64;
      kbox[k]  = rb[lr];
      karea[k] = ra[lr];
    }
    total = newtotal;
    __syncthreads();
    if (fin) break;
  }

  const int Kf = total;
  const float* bx = boxes  + (size_t)b * N * 4;
  const float* sc = scores + (size_t)b * N;
  const int*   lb = labels + (size_t)b * N;
  float4* obx = (float4*)out;
  float*  osc = out + (size_t)B * MAXDET * 4;
  float*  olb = osc + (size_t)B * MAXDET;
  float*  ovl = olb + (size_t)B * MAXDET;
  for (int rI = tid; rI < MAXDET; rI += NTHR) {
    size_t slot = (size_t)b * MAXDET + rI;
    if (rI < Kf) {
      int i = kept_sh[rI];
      unsigned orig = 0xFFFFFFFFu - (unsigned)(K[i] & 0xFFFFFFFFull);
      float4 bb = ((const float4*)bx)[orig];
      bb.x = clipf(bb.x, fimg);
      bb.y = clipf(bb.y, fimg);
      bb.z = clipf(bb.z, fimg);
      bb.w = clipf(bb.w, fimg);
      obx[slot] = bb;
      osc[slot] = sc[orig];
      olb[slot] = (float)lb[orig];
      ovl[slot] = 1.0f;
    } else {
      obx[slot] = make_float4(0.f, 0.f, 0.f, 0.f);
      osc[slot] = 0.0f;
      olb[slot] = 0.0f;
      ovl[slot] = 0.0f;
    }
  }
  if (tid == 0) { ws_K[b] = Kf; ws_done[b] = 1; }
}

// =================== R1: full 4-way merge (fallback path only) ===================
__global__ __launch_bounds__(NTHR)
void merge_full(const ull* __restrict__ ws_keys,
                const float* __restrict__ boxes,
                const int*   __restrict__ labels,
                const int*   __restrict__ img_i,
                int*    __restrict__ ws_sorted,
                float4* __restrict__ obox,
                float*  __restrict__ area,
                int N)
{
  __shared__ ull K[4096];
  const int b = blockIdx.x;
  const int tid = threadIdx.x;
  const ull* kb = ws_keys + (size_t)b * NBOX;
  for (int i = tid; i < 4096; i += NTHR) K[i] = kb[i];
  __syncthreads();
  { int i = tid;
    { ull a = K[i], c = K[2047 - i];        if (a < c) { K[i] = c; K[2047 - i] = a; } }
    { ull a = K[2048 + i], c = K[4095 - i]; if (a < c) { K[2048 + i] = c; K[4095 - i] = a; } } }
  __syncthreads();
  for (int j = 512; j >= 1; j >>= 1) {
    for (int idx = tid; idx < 4096; idx += NTHR) {
      int l = idx ^ j;
      if (l > idx) { ull a = K[idx], c = K[l]; if (a < c) { K[idx] = c; K[l] = a; } } }
    __syncthreads(); }
  for (int m = 0; m < 2; ++m) {
    int i2 = tid + m * 1024;
    ull a = K[i2], c = K[4095 - i2];
    if (a < c) { K[i2] = c; K[4095 - i2] = a; } }
  __syncthreads();
  for (int j = 1024; j >= 1; j >>= 1) {
    for (int idx = tid; idx < 4096; idx += NTHR) {
      int l = idx ^ j;
      if (l > idx) { ull a = K[idx], c = K[l]; if (a < c) { K[idx] = c; K[l] = a; } } }
    __syncthreads(); }

  float fimg = getimg(img_i);
  float offs = fimg + 1.0f;
  for (int idx = 1024 + tid; idx < 4096; idx += NTHR)
    emit_one(K[idx], idx, b, N, boxes, labels, fimg, offs, ws_sorted, obox, area);
}

// =================== fallback kernel (round-2 path, used if ws too small) ===================
struct SMB {
  float4       obox[CAP];
  unsigned int keepw[NWORDS];
  int          kept_pos[MAXDET];
  int          scal[4];
};

__global__ __launch_bounds__(NTHR)
void nms_kernel(const float* __restrict__ boxes,
                const float* __restrict__ scores,
                const int*   __restrict__ labels,
                const float* __restrict__ nms_th,
                const float* __restrict__ cls_w,
                const int*   __restrict__ img_i,
                float* __restrict__ out,
                int B, int N,
                const int* __restrict__ ws_sorted,
                const int* __restrict__ ws_V,
                float4* __restrict__ ws_ovf)
{
  __shared__ SMB sm;
  const int b    = blockIdx.x;
  const int tid  = threadIdx.x;

  const float* bx = boxes  + (size_t)b * N * 4;
  const float* sc = scores + (size_t)b * N;
  const int*   lb = labels + (size_t)b * N;
  const int*   so = ws_sorted + (size_t)b * N;

  float fimg = getimg(img_i);
  float off_scale = fimg + 1.0f;
  double xt = (double)(*nms_th);
  float  th = (float)(1.0 / (1.0 + exp(-xt)));

  const int V = ws_V[b];
  if (tid < 4) sm.scal[tid] = 0;

  for (int m = 0; m < 4; ++m) {
    int i = tid + m * NTHR;
    int orig = so[i];
    float4 bb = ((const float4*)bx)[orig];
    float off = (float)lb[orig] * off_scale;
    bb.x = clipf(bb.x, fimg) + off;
    bb.y = clipf(bb.y, fimg) + off;
    bb.z = clipf(bb.z, fimg) + off;
    bb.w = clipf(bb.w, fimg) + off;
    if (i < CAP) sm.obox[i] = bb;
    else         ws_ovf[(size_t)b * (NBOX - CAP) + (i - CAP)] = bb;
  }
  for (int w = tid; w < NWORDS; w += NTHR) {
    int lo = w * 32;
    unsigned val;
    if      (V >= lo + 32) val = 0xFFFFFFFFu;
    else if (V <= lo)      val = 0u;
    else                   val = (1u << (V - lo)) - 1u;
    sm.keepw[w] = val;
  }
  __syncthreads();

  const int nt = (V + 63) >> 6;
  int TR = 0;
  for (int t = 0; t < nt; ++t) {
    if (tid < 64) {
      int i0 = t * 64;
      int me = i0 + tid;
      float4 bb = (me < CAP) ? sm.obox[me]
                             : ws_ovf[(size_t)b * (NBOX - CAP) + (me - CAP)];
      float arJ = fmaxf(bb.z - bb.x, 0.0f) * fmaxf(bb.w - bb.y, 0.0f);
      ull supby = 0;
      for (int l = 0; l < 64; ++l) {
        int i = i0 + l;
        float4 bi = (i < CAP) ? sm.obox[i]
                              : ws_ovf[(size_t)b * (NBOX - CAP) + (i - CAP)];
        float ai = fmaxf(bi.z - bi.x, 0.0f) * fmaxf(bi.w - bi.y, 0.0f);
        float xx1 = fmaxf(bi.x, bb.x);
        float yy1 = fmaxf(bi.y, bb.y);
        float xx2 = fminf(bi.z, bb.z);
        float yy2 = fminf(bi.w, bb.w);
        float inter = fmaxf(xx2 - xx1, 0.0f) * fmaxf(yy2 - yy1, 0.0f);
        float denom = ai + arJ;
        denom = denom - inter;
        denom = denom + 1e-9f;
        float iou = inter / denom;
        if (iou > th) supby |= (1ull << l);
      }
      ull alive = ((ull)sm.keepw[2 * t + 1] << 32) | sm.keepw[2 * t];
      ull rem = alive;
      while (rem) {
        int l = __builtin_ctzll(rem);
        rem &= rem - 1;
        ull sup = __ballot((supby >> l) & 1ull);
        sup &= ((~1ull) << l);
        sup &= alive;
        alive &= ~sup;
        rem   &= ~sup;
      }
      if (tid == 0) {
        sm.keepw[2 * t]     = (unsigned)alive;
        sm.keepw[2 * t + 1] = (unsigned)(alive >> 32);
        atomicAdd(&sm.scal[1], __builtin_popcountll(alive));
      }
    }
    __syncthreads();
    TR = t + 1;
    if (sm.scal[1] >= MAXDET) break;

    int jstart = (t + 1) * 64;
    if (jstart < V) {
      ull alive = ((ull)sm.keepw[2 * t + 1] << 32) | sm.keepw[2 * t];
      if (alive) {
        for (int j = jstart + tid; j < V; j += NTHR) {
          unsigned wj = sm.keepw[j >> 5];
          if (!((wj >> (j & 31)) & 1u)) continue;
          float4 bj = (j < CAP) ? sm.obox[j]
                                : ws_ovf[(size_t)b * (NBOX - CAP) + (j - CAP)];
          float aj = fmaxf(bj.z - bj.x, 0.0f) * fmaxf(bj.w - bj.y, 0.0f);
          ull rem = alive;
          bool suppressed = false;
          while (rem) {
            int l = __builtin_ctzll(rem);
            rem &= rem - 1;
            int i = t * 64 + l;
            float4 bi = (i < CAP) ? sm.obox[i]
                                  : ws_ovf[(size_t)b * (NBOX - CAP) + (i - CAP)];
            float ai = fmaxf(bi.z - bi.x, 0.0f) * fmaxf(bi.w - bi.y, 0.0f);
            float xx1 = fmaxf(bi.x, bj.x);
            float yy1 = fmaxf(bi.y, bj.y);
            float xx2 = fminf(bi.z, bj.z);
            float yy2 = fminf(bi.w, bj.w);
            float inter = fmaxf(xx2 - xx1, 0.0f) * fmaxf(yy2 - yy1, 0.0f);
            float denom = ai + aj;
            denom = denom - inter;
            denom = denom + 1e-9f;
            float iou = inter / denom;
            if (iou > th) { suppressed = true; break; }
          }
          if (suppressed) atomicAnd(&sm.keepw[j >> 5], ~(1u << (j & 31)));
        }
      }
    }
    __syncthreads();
  }

  if (tid < NWORDS && tid >= TR * 2) sm.keepw[tid] = 0;
  __syncthreads();
  if (tid == 0) {
    int r = 0;
    for (int w = 0; w < NWORDS && r < MAXDET; ++w) {
      unsigned bits = sm.keepw[w];
      while (bits && r < MAXDET) {
        int l = __builtin_ctz(bits);
        bits &= bits - 1;
        sm.kept_pos[r++] = w * 32 + l;
      }
    }
    sm.scal[3] = r;
  }
  __syncthreads();
  const int K = sm.scal[3];

  float4* obx = (float4*)out;
  float*  osc = out + (size_t)B * MAXDET * 4;
  float*  olb = osc + (size_t)B * MAXDET;
  float*  ovl = olb + (size_t)B * MAXDET;
  for (int r = tid; r < MAXDET; r += NTHR) {
    size_t slot = (size_t)b * MAXDET + r;
    if (r < K) {
      int i    = sm.kept_pos[r];
      int orig = so[i];
      float4 bb = ((const float4*)bx)[orig];
      bb.x = clipf(bb.x, fimg);
      bb.y = clipf(bb.y, fimg);
      bb.z = clipf(bb.z, fimg);
      bb.w = clipf(bb.w, fimg);
      obx[slot] = bb;
      osc[slot] = sc[orig];
      olb[slot] = (float)lb[orig];
      ovl[slot] = 1.0f;
    } else {
      obx[slot] = make_float4(0.f, 0.f, 0.f, 0.f);
      osc[slot] = 0.0f;
      olb[slot] = 0.0f;
      ovl[slot] = 0.0f;
    }
  }
}

extern "C" void kernel_launch(void* const* d_in, const int* in_sizes, int n_in,
                              void* d_out, int out_size, void* d_ws, size_t ws_size,
                              hipStream_t stream) {
  const float* boxes      = (const float*)d_in[0];
  const float* scores     = (const float*)d_in[1];
  const int*   labels     = (const int*)d_in[2];
  const float* nms_thresh = (const float*)d_in[3];
  const float* cls_w      = (const float*)d_in[4];
  const int*   img_sz     = (const int*)d_in[5];

  int B = out_size / (MAXDET * 7);
  int N = in_sizes[1] / B;               // 4096

  // ws layout
  size_t off_sorted = 0;
  size_t off_V      = (off_sorted + (size_t)B * N * 4 + 255) & ~(size_t)255;
  size_t off_Vseg   = off_V + (size_t)B * 4;
  size_t off_done   = off_Vseg + (size_t)B * 16;
  size_t off_total  = off_done + (size_t)B * 4;
  size_t off_Kf     = off_total + (size_t)B * 4;
  size_t off_kw     = (off_Kf + (size_t)B * 4 + 255) & ~(size_t)255;
  size_t off_obox   = (off_kw + (size_t)B * 64 * 8 + 255) & ~(size_t)255;
  size_t off_area   = off_obox + (size_t)B * NBOX * 16;
  size_t off_keys   = (off_area + (size_t)B * NBOX * 4 + 255) & ~(size_t)255;
  size_t off_tr     = (off_keys + (size_t)B * NBOX * 8 + 255) & ~(size_t)255;
  size_t sz_tr      = (size_t)B * 16 * NBOX * 8;   // 8 MiB at B=16
  size_t need_fast  = off_tr + sz_tr;

  int*    ws_sorted = (int*)((char*)d_ws + off_sorted);
  int*    ws_V      = (int*)((char*)d_ws + off_V);
  int*    ws_Vseg   = (int*)((char*)d_ws + off_Vseg);
  int*    ws_done   = (int*)((char*)d_ws + off_done);
  int*    ws_total  = (int*)((char*)d_ws + off_total);
  int*    ws_K      = (int*)((char*)d_ws + off_Kf);
  ull*    ws_keptw  = (ull*)((char*)d_ws + off_kw);
  float4* obox      = (float4*)((char*)d_ws + off_obox);
  float*  area      = (float*)((char*)d_ws + off_area);
  ull*    ws_keys   = (ull*)((char*)d_ws + off_keys);
  ull*    trans     = (ull*)((char*)d_ws + off_tr);

  if (ws_size >= need_fast && N == NBOX) {
    sort_seg<<<dim3(4, B), dim3(256), 0, stream>>>(scores, labels, cls_w,
                                                   ws_keys, ws_Vseg, N);
    merge_top<<<dim3(B), dim3(512), 0, stream>>>(ws_keys, ws_Vseg, boxes, labels,
                                                 img_sz, ws_sorted, ws_V, ws_done,
                                                 obox, area, N);
    suptr0<<<dim3(136, B), dim3(256), 0, stream>>>(
        obox, area, nms_thresh, ws_V, trans);
    resolve0<<<dim3(B), dim3(NTHR), 0, stream>>>(
        boxes, scores, labels, img_sz, ws_V, trans,
        ws_done, ws_total, ws_keptw, ws_K, ws_sorted, (float*)d_out, B, N);
    cleanup_kernel<<<dim3(B), dim3(NTHR), 0, stream>>>(
        ws_keys, boxes, scores, labels, img_sz, nms_thresh, ws_V,
        ws_done, ws_total, ws_keptw, obox, ws_K, (float*)d_out, B, N);
  } else {
    sort_seg<<<dim3(4, B), dim3(256), 0, stream>>>(scores, labels, cls_w,
                                                   ws_keys, ws_Vseg, N);
    merge_top<<<dim3(B), dim3(512), 0, stream>>>(ws_keys, ws_Vseg, boxes, labels,
                                                 img_sz, ws_sorted, ws_V, ws_done,
                                                 obox, area, N);
    merge_full<<<dim3(B), dim3(NTHR), 0, stream>>>(
        ws_keys, boxes, labels, img_sz, ws_sorted, obox, area, N);
    float4* ws_ovf = (float4*)((char*)d_ws + off_keys);  // reuse keys tail region
    nms_kernel<<<dim3(B), dim3(NTHR), 0, stream>>>(boxes, scores, labels,
                                                   nms_thresh, cls_w, img_sz,
                                                   (float*)d_out, B, N,
                                                   ws_sorted, ws_V, ws_ovf);
  }
}